// Round 14
// baseline (299.810 us; speedup 1.0000x reference)
//
#include <hip/hip_runtime.h>
#include <hip/hip_bf16.h>
#include <math.h>

#define N_NODES 50000
#define N_EDGES 800000
#define ET_EDGES (N_EDGES + N_NODES)   // with self-loops
#define NEG_SLOPE 0.2f
#define NBUCK ((N_NODES + 255) / 256)  // 196 dst buckets (256 nodes each)
#define CHUNK 4096                      // edges per binning block
#define CAP   8192                      // scratch slots per bucket (>50 sigma)

typedef __hip_bfloat16 bf16;

__device__ inline float bfbits(unsigned short u) {
    return __uint_as_float(((unsigned)u) << 16);
}
__device__ inline float bflo(unsigned u) { return __uint_as_float(u << 16); }
__device__ inline float bfhi(unsigned u) { return __uint_as_float(u & 0xffff0000u); }

// ---------------- prep: detect dtype + convert params + init cursors --------
// Single block. Wave 0 detects (W1's first 128 halves viewed as bf16: all
// |v|<=64 iff data really is bf16 — P(false positive on fp32) ~ 6e-19).
// Then all 256 threads convert the 12 param tensors and init bucket cursors.
struct PrepArgs {
    const void* src[12];
    float*      dst[12];
    int         n[12];
};

__global__ __launch_bounds__(256)
void prep(PrepArgs a, const unsigned short* __restrict__ w1raw,
          unsigned* __restrict__ flag, int* __restrict__ cur256)
{
    __shared__ unsigned sflag;
    const int tid = threadIdx.x;
    if (tid < 64) {
        float v0 = bfbits(w1raw[2 * tid]);
        float v1 = bfbits(w1raw[2 * tid + 1]);
        bool bad = !(fabsf(v0) <= 64.f && fabsf(v1) <= 64.f);  // NaN -> bad
        unsigned long long b = __ballot(bad);
        if (tid == 0) { sflag = (b == 0ull) ? 1u : 0u; *flag = sflag; }
    }
    if (tid < NBUCK) cur256[tid] = tid * CAP;
    __syncthreads();
    const bool isbf = (sflag != 0u);
#pragma unroll
    for (int which = 0; which < 12; ++which) {
        const int n = a.n[which];
        const void* s = a.src[which];
        float* d = a.dst[which];
        for (int i = tid; i < n; i += 256)
            d[i] = isbf ? bfbits(((const unsigned short*)s)[i])
                        : ((const float*)s)[i];
    }
}

// ---------------- Pass C: bin edges into per-bucket scratch segments --------
__global__ __launch_bounds__(256)
void binpass(const int* __restrict__ ei, int* __restrict__ cur256,
             unsigned* __restrict__ scratch)
{
    __shared__ int hist[NBUCK];
    __shared__ int lpre[NBUCK + 1];
    __shared__ int lcur[NBUCK];
    __shared__ int gbase[NBUCK];
    __shared__ int scan_a[256];
    __shared__ unsigned entry[CHUNK];

    const int tid = threadIdx.x;
    const int e0  = blockIdx.x * CHUNK;
    const int n   = min(CHUNK, ET_EDGES - e0);

    if (tid < NBUCK) hist[tid] = 0;
    __syncthreads();

    for (int k = tid; k < n; k += 256) {
        int e = e0 + k;
        int d = (e < N_EDGES) ? ei[N_EDGES + e] : e - N_EDGES;
        atomicAdd(&hist[d >> 8], 1);
    }
    __syncthreads();

    int v = (tid < NBUCK) ? hist[tid] : 0;
    scan_a[tid] = v;
    __syncthreads();
    for (int off = 1; off < 256; off <<= 1) {
        int t = (tid >= off) ? scan_a[tid - off] : 0;
        __syncthreads();
        scan_a[tid] += t;
        __syncthreads();
    }
    if (tid < NBUCK) lpre[tid] = scan_a[tid] - v;
    if (tid == NBUCK - 1) lpre[NBUCK] = scan_a[tid];
    if (tid < NBUCK) {
        gbase[tid] = v ? atomicAdd(&cur256[tid], v) : 0;
        lcur[tid] = 0;
    }
    __syncthreads();

    for (int k = tid; k < n; k += 256) {
        int e = e0 + k;
        int s, d;
        if (e < N_EDGES) { s = ei[e]; d = ei[N_EDGES + e]; }
        else             { s = d = e - N_EDGES; }
        int b = d >> 8;
        int p = atomicAdd(&lcur[b], 1);
        entry[lpre[b] + p] = ((unsigned)s << 8) | (unsigned)(d & 255);
    }
    __syncthreads();

    for (int i = tid; i < n; i += 256) {
        int lo = 0, hi = NBUCK;
        while (hi - lo > 1) {
            int mid = (lo + hi) >> 1;
            if (lpre[mid] <= i) lo = mid; else hi = mid;
        }
        scratch[gbase[lo] + (i - lpre[lo])] = entry[i];
    }
}

// Pass D: inline bucket scan -> per-bucket node count/prefix -> rowptr +
// LDS-cursor scatter. (bucket_scan kernel folded in: every block recomputes
// the 196-wide exclusive scan of realized bucket counts — 8 LDS rounds.)
__global__ __launch_bounds__(256)
void fine_scatter(const int* __restrict__ cur256,
                  const unsigned* __restrict__ scratch,
                  int* __restrict__ csr_src,
                  int* __restrict__ rowptr)
{
    __shared__ int scnt[256];
    __shared__ int cnt[256];
    __shared__ int pre[256];
    const int tid = threadIdx.x;
    const int b   = blockIdx.x;
    const int nb  = b * 256;
    const int nn  = min(256, N_NODES - nb);

    // inline exclusive scan over realized bucket counts
    int bv = (tid < NBUCK) ? (cur256[tid] - tid * CAP) : 0;
    scnt[tid] = bv;
    __syncthreads();
    for (int off = 1; off < 256; off <<= 1) {
        int u = (tid >= off) ? scnt[tid - off] : 0;
        __syncthreads();
        scnt[tid] += u;
        __syncthreads();
    }
    const int gb = scnt[b] - (cur256[b] - b * CAP);   // exclusive prefix at b
    const int n  = cur256[b] - b * CAP;               // realized count
    const long seg = (long)b * CAP;

    cnt[tid] = 0;
    __syncthreads();
    for (int i = tid; i < n; i += 256)
        atomicAdd(&cnt[scratch[seg + i] & 255u], 1);
    __syncthreads();

    int v = cnt[tid];
    pre[tid] = v;
    __syncthreads();
    for (int off = 1; off < 256; off <<= 1) {
        int t = (tid >= off) ? pre[tid - off] : 0;
        __syncthreads();
        pre[tid] += t;
        __syncthreads();
    }
    int excl = pre[tid] - v + gb;
    if (tid < nn) rowptr[nb + tid] = excl;
    if (b == NBUCK - 1 && tid == 0) rowptr[N_NODES] = ET_EDGES;
    cnt[tid] = excl;    // reuse as cursors
    __syncthreads();

    for (int i = tid; i < n; i += 256) {
        unsigned e = scratch[seg + i];
        int p = atomicAdd(&cnt[e & 255u], 1);
        csr_src[p] = (int)(e >> 8);
    }
}

// ---------------- GEMM + alpha epilogue (32 rows/block, 8 rows/thread) ------
// XMODE: 1 = dtype-dynamic (layer 1 input), 2 = bf16 (internal layer io)
template<int CIN, int XMODE>
__global__ __launch_bounds__(256)
void gemm_alpha(const void* __restrict__ x,
                const float* __restrict__ W,
                const float* __restrict__ a_src,
                const float* __restrict__ a_dst,
                const unsigned* __restrict__ flag,
                bf16* __restrict__ hb,
                float* __restrict__ as_out,
                float* __restrict__ ad_out)
{
    __shared__ float sW[CIN * 64];
    __shared__ float sx[32 * CIN];
    const bool isbf = (XMODE == 2) || (XMODE == 1 && *flag != 0u);
    const int tid = threadIdx.x;
    const int col = tid & 63;
    const int wv  = tid >> 6;
    const int row0 = blockIdx.x * 32;

    for (int i = tid * 4; i < CIN * 64; i += 1024)
        *(float4*)&sW[i] = *(const float4*)&W[i];

    const long xbase = (long)row0 * CIN;
    const int  tile  = 32 * CIN;
    const int  limit = (N_NODES - row0) * CIN;   // multiple of 4
    if (isbf) {
        const unsigned short* xb = (const unsigned short*)x + xbase;
        for (int i = tid * 4; i < tile; i += 1024) {
            float4 v = {0.f, 0.f, 0.f, 0.f};
            if (i < limit) {
                ushort4 u = *(const ushort4*)&xb[i];
                v.x = bfbits(u.x); v.y = bfbits(u.y);
                v.z = bfbits(u.z); v.w = bfbits(u.w);
            }
            *(float4*)&sx[i] = v;
        }
    } else {
        const float* xf = (const float*)x + xbase;
        for (int i = tid * 4; i < tile; i += 1024) {
            float4 v = {0.f, 0.f, 0.f, 0.f};
            if (i < limit) v = *(const float4*)&xf[i];
            *(float4*)&sx[i] = v;
        }
    }
    __syncthreads();

    const int rbase = wv * 8;
    float acc[8];
#pragma unroll
    for (int r = 0; r < 8; ++r) acc[r] = 0.f;

#pragma unroll 2
    for (int kk = 0; kk < CIN; kk += 4) {
        float w0 = sW[(kk + 0) * 64 + col];
        float w1 = sW[(kk + 1) * 64 + col];
        float w2 = sW[(kk + 2) * 64 + col];
        float w3 = sW[(kk + 3) * 64 + col];
#pragma unroll
        for (int r = 0; r < 8; ++r) {
            const float4 xv = *(const float4*)&sx[(rbase + r) * CIN + kk];
            acc[r] = fmaf(xv.x, w0,
                     fmaf(xv.y, w1,
                     fmaf(xv.z, w2,
                     fmaf(xv.w, w3, acc[r]))));
        }
    }

    const float sa = a_src[col];
    const float sd = a_dst[col];
#pragma unroll
    for (int r = 0; r < 8; ++r) {
        int row = row0 + rbase + r;
        float vs = acc[r] * sa;
        float vd = acc[r] * sd;
#pragma unroll
        for (int off = 32; off > 0; off >>= 1) {
            vs += __shfl_xor(vs, off, 64);
            vd += __shfl_xor(vd, off, 64);
        }
        if (row < N_NODES) {
            hb[(long)row * 64 + col] = __float2bfloat16(acc[r]);
            if (col == 0) { as_out[row] = vs; ad_out[row] = vd; }
        }
    }
}

// ---------------- GAT gather: 16-lane group/node, no-max softmax ------------
#define EDGE4_FMA(wX, pX)                                                    \
    a0 = fmaf(wX, bflo(pX.x), a0); a1 = fmaf(wX, bfhi(pX.x), a1);            \
    a2 = fmaf(wX, bflo(pX.y), a2); a3 = fmaf(wX, bfhi(pX.y), a3);            \
    a4 = fmaf(wX, bflo(pX.z), a4); a5 = fmaf(wX, bfhi(pX.z), a5);            \
    a6 = fmaf(wX, bflo(pX.w), a6); a7 = fmaf(wX, bfhi(pX.w), a7);

template<bool DO_ELU, int OMODE>
__global__ __launch_bounds__(256)
void gat_gather(const int* __restrict__ rowptr,
                const int* __restrict__ csr_src,
                const float* __restrict__ as_in,
                const float* __restrict__ ad_in,
                const unsigned short* __restrict__ hb_in,
                const float* __restrict__ bias,
                void* __restrict__ out,
                const unsigned* __restrict__ flag)
{
    const int tid  = threadIdx.x;
    const int lane = tid & 63;
    const int l16  = lane & 15;
    const int gb16 = lane & 48;                    // group base within wave
    const int sub  = l16 >> 3;                     // edge slot 0/1
    const int c8   = (l16 & 7) * 8;                // channel group
    const int node = blockIdx.x * 16 + (tid >> 4); // 16 nodes per block
    if (node >= N_NODES) return;

    const int beg = rowptr[node];
    const int deg = rowptr[node + 1] - beg;
    const float adv = ad_in[node];

    // preload up to 32 edges: 2 per lane (src + unnormalized weight)
    int   msrc0 = 0, msrc1 = 0;
    float mw0 = 0.f, mw1 = 0.f;
    if (l16 < deg) {
        msrc0 = csr_src[beg + l16];
        float v = as_in[msrc0] + adv;
        v = (v > 0.f) ? v : NEG_SLOPE * v;
        mw0 = __expf(fminf(v, 60.f));
    }
    if (16 + l16 < deg) {
        msrc1 = csr_src[beg + 16 + l16];
        float v = as_in[msrc1] + adv;
        v = (v > 0.f) ? v : NEG_SLOPE * v;
        mw1 = __expf(fminf(v, 60.f));
    }

    float a0=0.f,a1=0.f,a2=0.f,a3=0.f,a4=0.f,a5=0.f,a6=0.f,a7=0.f,dsum=0.f;
    const int lim = (deg < 32) ? deg : 32;

    // bank 0: edges 0..15, 8 per iteration (4 loads in flight per lane)
#pragma unroll
    for (int j0 = 0; j0 < 16; j0 += 8) {
        if (j0 >= lim) break;
        const int jA = j0 + sub,     jB = j0 + 2 + sub;
        const int jC = j0 + 4 + sub, jD = j0 + 6 + sub;
        float wA = __shfl(mw0,   gb16 + jA, 64);
        int   sA = __shfl(msrc0, gb16 + jA, 64);
        float wB = __shfl(mw0,   gb16 + jB, 64);
        int   sB = __shfl(msrc0, gb16 + jB, 64);
        float wC = __shfl(mw0,   gb16 + jC, 64);
        int   sC = __shfl(msrc0, gb16 + jC, 64);
        float wD = __shfl(mw0,   gb16 + jD, 64);
        int   sD = __shfl(msrc0, gb16 + jD, 64);
        uint4 pA={0u,0u,0u,0u}, pB={0u,0u,0u,0u}, pC={0u,0u,0u,0u}, pD={0u,0u,0u,0u};
        const bool vA = jA < lim, vB = jB < lim, vC = jC < lim, vD = jD < lim;
        if (vA) pA = *(const uint4*)&hb_in[(long)sA * 64 + c8];
        if (vB) pB = *(const uint4*)&hb_in[(long)sB * 64 + c8];
        if (vC) pC = *(const uint4*)&hb_in[(long)sC * 64 + c8];
        if (vD) pD = *(const uint4*)&hb_in[(long)sD * 64 + c8];
        if (!vA) wA = 0.f;
        if (!vB) wB = 0.f;
        if (!vC) wC = 0.f;
        if (!vD) wD = 0.f;
        EDGE4_FMA(wA, pA) EDGE4_FMA(wB, pB) EDGE4_FMA(wC, pC) EDGE4_FMA(wD, pD)
        dsum += (wA + wB) + (wC + wD);
    }
    // bank 1: edges 16..31
#pragma unroll
    for (int j0 = 16; j0 < 32; j0 += 8) {
        if (j0 >= lim) break;
        const int jA = j0 + sub,     jB = j0 + 2 + sub;
        const int jC = j0 + 4 + sub, jD = j0 + 6 + sub;
        float wA = __shfl(mw1,   gb16 + jA - 16, 64);
        int   sA = __shfl(msrc1, gb16 + jA - 16, 64);
        float wB = __shfl(mw1,   gb16 + jB - 16, 64);
        int   sB = __shfl(msrc1, gb16 + jB - 16, 64);
        float wC = __shfl(mw1,   gb16 + jC - 16, 64);
        int   sC = __shfl(msrc1, gb16 + jC - 16, 64);
        float wD = __shfl(mw1,   gb16 + jD - 16, 64);
        int   sD = __shfl(msrc1, gb16 + jD - 16, 64);
        uint4 pA={0u,0u,0u,0u}, pB={0u,0u,0u,0u}, pC={0u,0u,0u,0u}, pD={0u,0u,0u,0u};
        const bool vA = jA < lim, vB = jB < lim, vC = jC < lim, vD = jD < lim;
        if (vA) pA = *(const uint4*)&hb_in[(long)sA * 64 + c8];
        if (vB) pB = *(const uint4*)&hb_in[(long)sB * 64 + c8];
        if (vC) pC = *(const uint4*)&hb_in[(long)sC * 64 + c8];
        if (vD) pD = *(const uint4*)&hb_in[(long)sD * 64 + c8];
        if (!vA) wA = 0.f;
        if (!vB) wB = 0.f;
        if (!vC) wC = 0.f;
        if (!vD) wD = 0.f;
        EDGE4_FMA(wA, pA) EDGE4_FMA(wB, pB) EDGE4_FMA(wC, pC) EDGE4_FMA(wD, pD)
        dsum += (wA + wB) + (wC + wD);
    }
    // rare tail: deg > 32
    for (int j0 = 32; j0 < deg; j0 += 2) {
        const int j = j0 + sub;
        if (j < deg) {
            int sj = csr_src[beg + j];
            float v = as_in[sj] + adv;
            v = (v > 0.f) ? v : NEG_SLOPE * v;
            float wj = __expf(fminf(v, 60.f));
            const uint4 p = *(const uint4*)&hb_in[(long)sj * 64 + c8];
            EDGE4_FMA(wj, p)
            dsum += wj;
        }
    }

    a0 += __shfl_xor(a0, 8, 64); a1 += __shfl_xor(a1, 8, 64);
    a2 += __shfl_xor(a2, 8, 64); a3 += __shfl_xor(a3, 8, 64);
    a4 += __shfl_xor(a4, 8, 64); a5 += __shfl_xor(a5, 8, 64);
    a6 += __shfl_xor(a6, 8, 64); a7 += __shfl_xor(a7, 8, 64);
    dsum += __shfl_xor(dsum, 8, 64);

    if (sub == 0) {   // lanes l16 0..7 hold channels c8..c8+7
        float inv = 1.f / dsum;
        float r[8] = {a0, a1, a2, a3, a4, a5, a6, a7};
#pragma unroll
        for (int k = 0; k < 8; ++k) {
            r[k] = r[k] * inv + bias[c8 + k];
            if (DO_ELU) r[k] = (r[k] > 0.f) ? r[k] : expm1f(r[k]);
        }
        long o = (long)node * 64 + c8;
        bool bfst = (OMODE == 0) || (*flag != 0u);
        if (bfst) {
            uint4 u;
            u.x = ((unsigned)__bfloat16_as_ushort(__float2bfloat16(r[0]))) |
                  (((unsigned)__bfloat16_as_ushort(__float2bfloat16(r[1]))) << 16);
            u.y = ((unsigned)__bfloat16_as_ushort(__float2bfloat16(r[2]))) |
                  (((unsigned)__bfloat16_as_ushort(__float2bfloat16(r[3]))) << 16);
            u.z = ((unsigned)__bfloat16_as_ushort(__float2bfloat16(r[4]))) |
                  (((unsigned)__bfloat16_as_ushort(__float2bfloat16(r[5]))) << 16);
            u.w = ((unsigned)__bfloat16_as_ushort(__float2bfloat16(r[6]))) |
                  (((unsigned)__bfloat16_as_ushort(__float2bfloat16(r[7]))) << 16);
            *(uint4*)&((unsigned short*)out)[o] = u;
        } else {
            float4 f0 = {r[0], r[1], r[2], r[3]};
            float4 f1 = {r[4], r[5], r[6], r[7]};
            *(float4*)&((float*)out)[o]     = f0;
            *(float4*)&((float*)out)[o + 4] = f1;
        }
    }
}

extern "C" void kernel_launch(void* const* d_in, const int* in_sizes, int n_in,
                              void* d_out, int out_size, void* d_ws, size_t ws_size,
                              hipStream_t stream)
{
    const void* x  = d_in[0];
    const int*  ei = (const int*)d_in[1];
    const void* pW1 = d_in[2],  *pas1 = d_in[3],  *pad1 = d_in[4],  *pb1 = d_in[5];
    const void* pW2 = d_in[6],  *pas2 = d_in[7],  *pad2 = d_in[8],  *pb2 = d_in[9];
    const void* pW3 = d_in[10], *pas3 = d_in[11], *pad3 = d_in[12], *pb3 = d_in[13];

    float* ws = (float*)d_ws;
    bf16*     hbA    = (bf16*)ws;                              // 6.4 MB
    bf16*     hbB    = (bf16*)(ws + (long)N_NODES * 32);       // 6.4 MB
    float*    as_    = ws + (long)N_NODES * 64;
    float*    ad_    = as_ + N_NODES;
    int*      cur256 = (int*)(ad_ + N_NODES);                  // NBUCK
    int*      rowptr = cur256 + NBUCK;                         // N+1
    int*      csr_src= rowptr + N_NODES + 1;                   // 3.4 MB
    unsigned* scratch= (unsigned*)(csr_src + ET_EDGES);        // NBUCK*CAP 6.4 MB
    float*    prm    = (float*)(scratch + (long)NBUCK * CAP);
    unsigned* flag   = (unsigned*)(prm + 20000);

    float* W1 = prm;     float* as1 = W1 + 8192; float* ad1 = as1 + 64; float* b1 = ad1 + 64;
    float* W2 = b1 + 64; float* as2 = W2 + 4096; float* ad2 = as2 + 64; float* b2 = ad2 + 64;
    float* W3 = b2 + 64; float* as3 = W3 + 4096; float* ad3 = as3 + 64; float* b3 = ad3 + 64;

    PrepArgs pa;
    const void* srcs[12] = {pW1, pas1, pad1, pb1, pW2, pas2, pad2, pb2, pW3, pas3, pad3, pb3};
    float*      dsts[12] = {W1, as1, ad1, b1, W2, as2, ad2, b2, W3, as3, ad3, b3};
    int         ns[12]   = {8192, 64, 64, 64, 4096, 64, 64, 64, 4096, 64, 64, 64};
    for (int i = 0; i < 12; ++i) { pa.src[i] = srcs[i]; pa.dst[i] = dsts[i]; pa.n[i] = ns[i]; }
    prep<<<1, 256, 0, stream>>>(pa, (const unsigned short*)pW1, flag, cur256);

    // ---- CSR build: segment-append binpass -> fine scatter (inline scan) ----
    const int chunk_grid = (ET_EDGES + CHUNK - 1) / CHUNK;
    binpass<<<chunk_grid, 256, 0, stream>>>(ei, cur256, scratch);
    fine_scatter<<<NBUCK, 256, 0, stream>>>(cur256, scratch, csr_src, rowptr);

    const int gemm_grid = (N_NODES + 31) / 32;
    const int gat_grid  = (N_NODES + 15) / 16;

    // ---------- Layer 1 ----------
    gemm_alpha<128, 1><<<gemm_grid, 256, 0, stream>>>(
        x, W1, as1, ad1, flag, hbA, as_, ad_);
    gat_gather<true, 0><<<gat_grid, 256, 0, stream>>>(
        rowptr, csr_src, as_, ad_, (const unsigned short*)hbA, b1, hbB, flag);

    // ---------- Layer 2 (bf16 layer io) ----------
    gemm_alpha<64, 2><<<gemm_grid, 256, 0, stream>>>(
        hbB, W2, as2, ad2, flag, hbA, as_, ad_);
    gat_gather<true, 0><<<gat_grid, 256, 0, stream>>>(
        rowptr, csr_src, as_, ad_, (const unsigned short*)hbA, b2, hbB, flag);

    // ---------- Layer 3 ----------
    gemm_alpha<64, 2><<<gemm_grid, 256, 0, stream>>>(
        hbB, W3, as3, ad3, flag, hbA, as_, ad_);
    gat_gather<false, 1><<<gat_grid, 256, 0, stream>>>(
        rowptr, csr_src, as_, ad_, (const unsigned short*)hbA, b3, d_out, flag);
}

// Round 15
// 278.196 us; speedup vs baseline: 1.0777x; 1.0777x over previous
//
#include <hip/hip_runtime.h>
#include <hip/hip_bf16.h>
#include <math.h>

#define N_NODES 50000
#define N_EDGES 800000
#define ET_EDGES (N_EDGES + N_NODES)   // with self-loops
#define NEG_SLOPE 0.2f
#define NBUCK ((N_NODES + 255) / 256)  // 196 dst buckets (256 nodes each)
#define CHUNK 4096                      // edges per binning block
#define CAP   8192                      // scratch slots per bucket (>50 sigma)

typedef __hip_bfloat16 bf16;

__device__ inline float bfbits(unsigned short u) {
    return __uint_as_float(((unsigned)u) << 16);
}
__device__ inline float bflo(unsigned u) { return __uint_as_float(u << 16); }
__device__ inline float bfhi(unsigned u) { return __uint_as_float(u & 0xffff0000u); }

// ---------------- prep: convert params (parallel) + init cursors + flag -----
// grid = dim3(8, 13). Every block re-detects dtype inline from W1's first 128
// halves (cheap; P(fp32 false-positive) ~ 6e-19) — no serial detect dispatch.
// Slices y<12 convert the 12 param tensors; slice y==12 inits cursors + flag.
struct PrepArgs {
    const void* src[12];
    float*      dst[12];
    int         n[12];
};

__global__ __launch_bounds__(256)
void prep(PrepArgs a, const unsigned short* __restrict__ w1raw,
          unsigned* __restrict__ flag, int* __restrict__ cur256)
{
    __shared__ unsigned sflag;
    const int tid = threadIdx.x;
    if (tid < 64) {
        float v0 = bfbits(w1raw[2 * tid]);
        float v1 = bfbits(w1raw[2 * tid + 1]);
        bool bad = !(fabsf(v0) <= 64.f && fabsf(v1) <= 64.f);  // NaN -> bad
        unsigned long long b = __ballot(bad);
        if (tid == 0) sflag = (b == 0ull) ? 1u : 0u;
    }
    __syncthreads();
    const bool isbf = (sflag != 0u);
    const int which = blockIdx.y;

    if (which == 12) {
        int i = blockIdx.x * 256 + tid;
        if (i < NBUCK) cur256[i] = i * CAP;
        if (blockIdx.x == 0 && tid == 0) *flag = isbf ? 1u : 0u;
        return;
    }
    const int n = a.n[which];
    const void* s = a.src[which];
    float* d = a.dst[which];
    for (int i = blockIdx.x * 256 + tid; i < n; i += 8 * 256)
        d[i] = isbf ? bfbits(((const unsigned short*)s)[i])
                    : ((const float*)s)[i];
}

// ---------------- Pass C: bin edges into per-bucket scratch segments --------
__global__ __launch_bounds__(256)
void binpass(const int* __restrict__ ei, int* __restrict__ cur256,
             unsigned* __restrict__ scratch)
{
    __shared__ int hist[NBUCK];
    __shared__ int lpre[NBUCK + 1];
    __shared__ int lcur[NBUCK];
    __shared__ int gbase[NBUCK];
    __shared__ int scan_a[256];
    __shared__ unsigned entry[CHUNK];

    const int tid = threadIdx.x;
    const int e0  = blockIdx.x * CHUNK;
    const int n   = min(CHUNK, ET_EDGES - e0);

    if (tid < NBUCK) hist[tid] = 0;
    __syncthreads();

    for (int k = tid; k < n; k += 256) {
        int e = e0 + k;
        int d = (e < N_EDGES) ? ei[N_EDGES + e] : e - N_EDGES;
        atomicAdd(&hist[d >> 8], 1);
    }
    __syncthreads();

    int v = (tid < NBUCK) ? hist[tid] : 0;
    scan_a[tid] = v;
    __syncthreads();
    for (int off = 1; off < 256; off <<= 1) {
        int t = (tid >= off) ? scan_a[tid - off] : 0;
        __syncthreads();
        scan_a[tid] += t;
        __syncthreads();
    }
    if (tid < NBUCK) lpre[tid] = scan_a[tid] - v;
    if (tid == NBUCK - 1) lpre[NBUCK] = scan_a[tid];
    if (tid < NBUCK) {
        gbase[tid] = v ? atomicAdd(&cur256[tid], v) : 0;
        lcur[tid] = 0;
    }
    __syncthreads();

    for (int k = tid; k < n; k += 256) {
        int e = e0 + k;
        int s, d;
        if (e < N_EDGES) { s = ei[e]; d = ei[N_EDGES + e]; }
        else             { s = d = e - N_EDGES; }
        int b = d >> 8;
        int p = atomicAdd(&lcur[b], 1);
        entry[lpre[b] + p] = ((unsigned)s << 8) | (unsigned)(d & 255);
    }
    __syncthreads();

    for (int i = tid; i < n; i += 256) {
        int lo = 0, hi = NBUCK;
        while (hi - lo > 1) {
            int mid = (lo + hi) >> 1;
            if (lpre[mid] <= i) lo = mid; else hi = mid;
        }
        scratch[gbase[lo] + (i - lpre[lo])] = entry[i];
    }
}

// Pass D: inline bucket scan -> per-bucket node count/prefix -> rowptr +
// LDS-cursor scatter. (bucket_scan folded in: 196-wide scan is 8 LDS rounds.)
__global__ __launch_bounds__(256)
void fine_scatter(const int* __restrict__ cur256,
                  const unsigned* __restrict__ scratch,
                  int* __restrict__ csr_src,
                  int* __restrict__ rowptr)
{
    __shared__ int scnt[256];
    __shared__ int cnt[256];
    __shared__ int pre[256];
    const int tid = threadIdx.x;
    const int b   = blockIdx.x;
    const int nb  = b * 256;
    const int nn  = min(256, N_NODES - nb);

    // inline exclusive scan over realized bucket counts
    int bv = (tid < NBUCK) ? (cur256[tid] - tid * CAP) : 0;
    scnt[tid] = bv;
    __syncthreads();
    for (int off = 1; off < 256; off <<= 1) {
        int u = (tid >= off) ? scnt[tid - off] : 0;
        __syncthreads();
        scnt[tid] += u;
        __syncthreads();
    }
    const int gb = scnt[b] - (cur256[b] - b * CAP);   // exclusive prefix at b
    const int n  = cur256[b] - b * CAP;               // realized count
    const long seg = (long)b * CAP;

    cnt[tid] = 0;
    __syncthreads();
    for (int i = tid; i < n; i += 256)
        atomicAdd(&cnt[scratch[seg + i] & 255u], 1);
    __syncthreads();

    int v = cnt[tid];
    pre[tid] = v;
    __syncthreads();
    for (int off = 1; off < 256; off <<= 1) {
        int t = (tid >= off) ? pre[tid - off] : 0;
        __syncthreads();
        pre[tid] += t;
        __syncthreads();
    }
    int excl = pre[tid] - v + gb;
    if (tid < nn) rowptr[nb + tid] = excl;
    if (b == NBUCK - 1 && tid == 0) rowptr[N_NODES] = ET_EDGES;
    cnt[tid] = excl;    // reuse as cursors
    __syncthreads();

    for (int i = tid; i < n; i += 256) {
        unsigned e = scratch[seg + i];
        int p = atomicAdd(&cnt[e & 255u], 1);
        csr_src[p] = (int)(e >> 8);
    }
}

// ---------------- GEMM + alpha epilogue (32 rows/block, 8 rows/thread) ------
// XMODE: 1 = dtype-dynamic (layer 1 input), 2 = bf16 (internal layer io)
template<int CIN, int XMODE>
__global__ __launch_bounds__(256)
void gemm_alpha(const void* __restrict__ x,
                const float* __restrict__ W,
                const float* __restrict__ a_src,
                const float* __restrict__ a_dst,
                const unsigned* __restrict__ flag,
                bf16* __restrict__ hb,
                float* __restrict__ as_out,
                float* __restrict__ ad_out)
{
    __shared__ float sW[CIN * 64];
    __shared__ float sx[32 * CIN];
    const bool isbf = (XMODE == 2) || (XMODE == 1 && *flag != 0u);
    const int tid = threadIdx.x;
    const int col = tid & 63;
    const int wv  = tid >> 6;
    const int row0 = blockIdx.x * 32;

    for (int i = tid * 4; i < CIN * 64; i += 1024)
        *(float4*)&sW[i] = *(const float4*)&W[i];

    const long xbase = (long)row0 * CIN;
    const int  tile  = 32 * CIN;
    const int  limit = (N_NODES - row0) * CIN;   // multiple of 4
    if (isbf) {
        const unsigned short* xb = (const unsigned short*)x + xbase;
        for (int i = tid * 4; i < tile; i += 1024) {
            float4 v = {0.f, 0.f, 0.f, 0.f};
            if (i < limit) {
                ushort4 u = *(const ushort4*)&xb[i];
                v.x = bfbits(u.x); v.y = bfbits(u.y);
                v.z = bfbits(u.z); v.w = bfbits(u.w);
            }
            *(float4*)&sx[i] = v;
        }
    } else {
        const float* xf = (const float*)x + xbase;
        for (int i = tid * 4; i < tile; i += 1024) {
            float4 v = {0.f, 0.f, 0.f, 0.f};
            if (i < limit) v = *(const float4*)&xf[i];
            *(float4*)&sx[i] = v;
        }
    }
    __syncthreads();

    const int rbase = wv * 8;
    float acc[8];
#pragma unroll
    for (int r = 0; r < 8; ++r) acc[r] = 0.f;

#pragma unroll 2
    for (int kk = 0; kk < CIN; kk += 4) {
        float w0 = sW[(kk + 0) * 64 + col];
        float w1 = sW[(kk + 1) * 64 + col];
        float w2 = sW[(kk + 2) * 64 + col];
        float w3 = sW[(kk + 3) * 64 + col];
#pragma unroll
        for (int r = 0; r < 8; ++r) {
            const float4 xv = *(const float4*)&sx[(rbase + r) * CIN + kk];
            acc[r] = fmaf(xv.x, w0,
                     fmaf(xv.y, w1,
                     fmaf(xv.z, w2,
                     fmaf(xv.w, w3, acc[r]))));
        }
    }

    const float sa = a_src[col];
    const float sd = a_dst[col];
#pragma unroll
    for (int r = 0; r < 8; ++r) {
        int row = row0 + rbase + r;
        float vs = acc[r] * sa;
        float vd = acc[r] * sd;
#pragma unroll
        for (int off = 32; off > 0; off >>= 1) {
            vs += __shfl_xor(vs, off, 64);
            vd += __shfl_xor(vd, off, 64);
        }
        if (row < N_NODES) {
            hb[(long)row * 64 + col] = __float2bfloat16(acc[r]);
            if (col == 0) { as_out[row] = vs; ad_out[row] = vd; }
        }
    }
}

// ---------------- GAT gather: 16-lane group/node, no-max softmax ------------
#define EDGE4_FMA(wX, pX)                                                    \
    a0 = fmaf(wX, bflo(pX.x), a0); a1 = fmaf(wX, bfhi(pX.x), a1);            \
    a2 = fmaf(wX, bflo(pX.y), a2); a3 = fmaf(wX, bfhi(pX.y), a3);            \
    a4 = fmaf(wX, bflo(pX.z), a4); a5 = fmaf(wX, bfhi(pX.z), a5);            \
    a6 = fmaf(wX, bflo(pX.w), a6); a7 = fmaf(wX, bfhi(pX.w), a7);

template<bool DO_ELU, int OMODE>
__global__ __launch_bounds__(256)
void gat_gather(const int* __restrict__ rowptr,
                const int* __restrict__ csr_src,
                const float* __restrict__ as_in,
                const float* __restrict__ ad_in,
                const unsigned short* __restrict__ hb_in,
                const float* __restrict__ bias,
                void* __restrict__ out,
                const unsigned* __restrict__ flag)
{
    const int tid  = threadIdx.x;
    const int lane = tid & 63;
    const int l16  = lane & 15;
    const int gb16 = lane & 48;                    // group base within wave
    const int sub  = l16 >> 3;                     // edge slot 0/1
    const int c8   = (l16 & 7) * 8;                // channel group
    const int node = blockIdx.x * 16 + (tid >> 4); // 16 nodes per block
    if (node >= N_NODES) return;

    const int beg = rowptr[node];
    const int deg = rowptr[node + 1] - beg;
    const float adv = ad_in[node];

    // preload up to 32 edges: 2 per lane (src + unnormalized weight)
    int   msrc0 = 0, msrc1 = 0;
    float mw0 = 0.f, mw1 = 0.f;
    if (l16 < deg) {
        msrc0 = csr_src[beg + l16];
        float v = as_in[msrc0] + adv;
        v = (v > 0.f) ? v : NEG_SLOPE * v;
        mw0 = __expf(fminf(v, 60.f));
    }
    if (16 + l16 < deg) {
        msrc1 = csr_src[beg + 16 + l16];
        float v = as_in[msrc1] + adv;
        v = (v > 0.f) ? v : NEG_SLOPE * v;
        mw1 = __expf(fminf(v, 60.f));
    }

    float a0=0.f,a1=0.f,a2=0.f,a3=0.f,a4=0.f,a5=0.f,a6=0.f,a7=0.f,dsum=0.f;
    const int lim = (deg < 32) ? deg : 32;

    // bank 0: edges 0..15, 8 per iteration (4 loads in flight per lane)
#pragma unroll
    for (int j0 = 0; j0 < 16; j0 += 8) {
        if (j0 >= lim) break;
        const int jA = j0 + sub,     jB = j0 + 2 + sub;
        const int jC = j0 + 4 + sub, jD = j0 + 6 + sub;
        float wA = __shfl(mw0,   gb16 + jA, 64);
        int   sA = __shfl(msrc0, gb16 + jA, 64);
        float wB = __shfl(mw0,   gb16 + jB, 64);
        int   sB = __shfl(msrc0, gb16 + jB, 64);
        float wC = __shfl(mw0,   gb16 + jC, 64);
        int   sC = __shfl(msrc0, gb16 + jC, 64);
        float wD = __shfl(mw0,   gb16 + jD, 64);
        int   sD = __shfl(msrc0, gb16 + jD, 64);
        uint4 pA={0u,0u,0u,0u}, pB={0u,0u,0u,0u}, pC={0u,0u,0u,0u}, pD={0u,0u,0u,0u};
        const bool vA = jA < lim, vB = jB < lim, vC = jC < lim, vD = jD < lim;
        if (vA) pA = *(const uint4*)&hb_in[(long)sA * 64 + c8];
        if (vB) pB = *(const uint4*)&hb_in[(long)sB * 64 + c8];
        if (vC) pC = *(const uint4*)&hb_in[(long)sC * 64 + c8];
        if (vD) pD = *(const uint4*)&hb_in[(long)sD * 64 + c8];
        if (!vA) wA = 0.f;
        if (!vB) wB = 0.f;
        if (!vC) wC = 0.f;
        if (!vD) wD = 0.f;
        EDGE4_FMA(wA, pA) EDGE4_FMA(wB, pB) EDGE4_FMA(wC, pC) EDGE4_FMA(wD, pD)
        dsum += (wA + wB) + (wC + wD);
    }
    // bank 1: edges 16..31
#pragma unroll
    for (int j0 = 16; j0 < 32; j0 += 8) {
        if (j0 >= lim) break;
        const int jA = j0 + sub,     jB = j0 + 2 + sub;
        const int jC = j0 + 4 + sub, jD = j0 + 6 + sub;
        float wA = __shfl(mw1,   gb16 + jA - 16, 64);
        int   sA = __shfl(msrc1, gb16 + jA - 16, 64);
        float wB = __shfl(mw1,   gb16 + jB - 16, 64);
        int   sB = __shfl(msrc1, gb16 + jB - 16, 64);
        float wC = __shfl(mw1,   gb16 + jC - 16, 64);
        int   sC = __shfl(msrc1, gb16 + jC - 16, 64);
        float wD = __shfl(mw1,   gb16 + jD - 16, 64);
        int   sD = __shfl(msrc1, gb16 + jD - 16, 64);
        uint4 pA={0u,0u,0u,0u}, pB={0u,0u,0u,0u}, pC={0u,0u,0u,0u}, pD={0u,0u,0u,0u};
        const bool vA = jA < lim, vB = jB < lim, vC = jC < lim, vD = jD < lim;
        if (vA) pA = *(const uint4*)&hb_in[(long)sA * 64 + c8];
        if (vB) pB = *(const uint4*)&hb_in[(long)sB * 64 + c8];
        if (vC) pC = *(const uint4*)&hb_in[(long)sC * 64 + c8];
        if (vD) pD = *(const uint4*)&hb_in[(long)sD * 64 + c8];
        if (!vA) wA = 0.f;
        if (!vB) wB = 0.f;
        if (!vC) wC = 0.f;
        if (!vD) wD = 0.f;
        EDGE4_FMA(wA, pA) EDGE4_FMA(wB, pB) EDGE4_FMA(wC, pC) EDGE4_FMA(wD, pD)
        dsum += (wA + wB) + (wC + wD);
    }
    // rare tail: deg > 32
    for (int j0 = 32; j0 < deg; j0 += 2) {
        const int j = j0 + sub;
        if (j < deg) {
            int sj = csr_src[beg + j];
            float v = as_in[sj] + adv;
            v = (v > 0.f) ? v : NEG_SLOPE * v;
            float wj = __expf(fminf(v, 60.f));
            const uint4 p = *(const uint4*)&hb_in[(long)sj * 64 + c8];
            EDGE4_FMA(wj, p)
            dsum += wj;
        }
    }

    a0 += __shfl_xor(a0, 8, 64); a1 += __shfl_xor(a1, 8, 64);
    a2 += __shfl_xor(a2, 8, 64); a3 += __shfl_xor(a3, 8, 64);
    a4 += __shfl_xor(a4, 8, 64); a5 += __shfl_xor(a5, 8, 64);
    a6 += __shfl_xor(a6, 8, 64); a7 += __shfl_xor(a7, 8, 64);
    dsum += __shfl_xor(dsum, 8, 64);

    if (sub == 0) {   // lanes l16 0..7 hold channels c8..c8+7
        float inv = 1.f / dsum;
        float r[8] = {a0, a1, a2, a3, a4, a5, a6, a7};
#pragma unroll
        for (int k = 0; k < 8; ++k) {
            r[k] = r[k] * inv + bias[c8 + k];
            if (DO_ELU) r[k] = (r[k] > 0.f) ? r[k] : expm1f(r[k]);
        }
        long o = (long)node * 64 + c8;
        bool bfst = (OMODE == 0) || (*flag != 0u);
        if (bfst) {
            uint4 u;
            u.x = ((unsigned)__bfloat16_as_ushort(__float2bfloat16(r[0]))) |
                  (((unsigned)__bfloat16_as_ushort(__float2bfloat16(r[1]))) << 16);
            u.y = ((unsigned)__bfloat16_as_ushort(__float2bfloat16(r[2]))) |
                  (((unsigned)__bfloat16_as_ushort(__float2bfloat16(r[3]))) << 16);
            u.z = ((unsigned)__bfloat16_as_ushort(__float2bfloat16(r[4]))) |
                  (((unsigned)__bfloat16_as_ushort(__float2bfloat16(r[5]))) << 16);
            u.w = ((unsigned)__bfloat16_as_ushort(__float2bfloat16(r[6]))) |
                  (((unsigned)__bfloat16_as_ushort(__float2bfloat16(r[7]))) << 16);
            *(uint4*)&((unsigned short*)out)[o] = u;
        } else {
            float4 f0 = {r[0], r[1], r[2], r[3]};
            float4 f1 = {r[4], r[5], r[6], r[7]};
            *(float4*)&((float*)out)[o]     = f0;
            *(float4*)&((float*)out)[o + 4] = f1;
        }
    }
}

extern "C" void kernel_launch(void* const* d_in, const int* in_sizes, int n_in,
                              void* d_out, int out_size, void* d_ws, size_t ws_size,
                              hipStream_t stream)
{
    const void* x  = d_in[0];
    const int*  ei = (const int*)d_in[1];
    const void* pW1 = d_in[2],  *pas1 = d_in[3],  *pad1 = d_in[4],  *pb1 = d_in[5];
    const void* pW2 = d_in[6],  *pas2 = d_in[7],  *pad2 = d_in[8],  *pb2 = d_in[9];
    const void* pW3 = d_in[10], *pas3 = d_in[11], *pad3 = d_in[12], *pb3 = d_in[13];

    float* ws = (float*)d_ws;
    bf16*     hbA    = (bf16*)ws;                              // 6.4 MB
    bf16*     hbB    = (bf16*)(ws + (long)N_NODES * 32);       // 6.4 MB
    float*    as_    = ws + (long)N_NODES * 64;
    float*    ad_    = as_ + N_NODES;
    int*      cur256 = (int*)(ad_ + N_NODES);                  // NBUCK
    int*      rowptr = cur256 + NBUCK;                         // N+1
    int*      csr_src= rowptr + N_NODES + 1;                   // 3.4 MB
    unsigned* scratch= (unsigned*)(csr_src + ET_EDGES);        // NBUCK*CAP 6.4 MB
    float*    prm    = (float*)(scratch + (long)NBUCK * CAP);
    unsigned* flag   = (unsigned*)(prm + 20000);

    float* W1 = prm;     float* as1 = W1 + 8192; float* ad1 = as1 + 64; float* b1 = ad1 + 64;
    float* W2 = b1 + 64; float* as2 = W2 + 4096; float* ad2 = as2 + 64; float* b2 = ad2 + 64;
    float* W3 = b2 + 64; float* as3 = W3 + 4096; float* ad3 = as3 + 64; float* b3 = ad3 + 64;

    PrepArgs pa;
    const void* srcs[12] = {pW1, pas1, pad1, pb1, pW2, pas2, pad2, pb2, pW3, pas3, pad3, pb3};
    float*      dsts[12] = {W1, as1, ad1, b1, W2, as2, ad2, b2, W3, as3, ad3, b3};
    int         ns[12]   = {8192, 64, 64, 64, 4096, 64, 64, 64, 4096, 64, 64, 64};
    for (int i = 0; i < 12; ++i) { pa.src[i] = srcs[i]; pa.dst[i] = dsts[i]; pa.n[i] = ns[i]; }
    prep<<<dim3(8, 13), 256, 0, stream>>>(pa, (const unsigned short*)pW1, flag, cur256);

    // ---- CSR build: segment-append binpass -> fine scatter (inline scan) ----
    const int chunk_grid = (ET_EDGES + CHUNK - 1) / CHUNK;
    binpass<<<chunk_grid, 256, 0, stream>>>(ei, cur256, scratch);
    fine_scatter<<<NBUCK, 256, 0, stream>>>(cur256, scratch, csr_src, rowptr);

    const int gemm_grid = (N_NODES + 31) / 32;
    const int gat_grid  = (N_NODES + 15) / 16;

    // ---------- Layer 1 ----------
    gemm_alpha<128, 1><<<gemm_grid, 256, 0, stream>>>(
        x, W1, as1, ad1, flag, hbA, as_, ad_);
    gat_gather<true, 0><<<gat_grid, 256, 0, stream>>>(
        rowptr, csr_src, as_, ad_, (const unsigned short*)hbA, b1, hbB, flag);

    // ---------- Layer 2 (bf16 layer io) ----------
    gemm_alpha<64, 2><<<gemm_grid, 256, 0, stream>>>(
        hbB, W2, as2, ad2, flag, hbA, as_, ad_);
    gat_gather<true, 0><<<gat_grid, 256, 0, stream>>>(
        rowptr, csr_src, as_, ad_, (const unsigned short*)hbA, b2, hbB, flag);

    // ---------- Layer 3 ----------
    gemm_alpha<64, 2><<<gemm_grid, 256, 0, stream>>>(
        hbB, W3, as3, ad3, flag, hbA, as_, ad_);
    gat_gather<false, 1><<<gat_grid, 256, 0, stream>>>(
        rowptr, csr_src, as_, ad_, (const unsigned short*)hbA, b3, d_out, flag);
}